// Round 3
// baseline (428.318 us; speedup 1.0000x reference)
//
#include <hip/hip_runtime.h>

// ===========================================================================
// ROUND 3 — DIAGNOSTIC BUILD (chain-doubling calibration).
// Kernels are byte-identical to the 354 µs baseline (R2, plain stores).
// kernel_launch runs the chain TWICE in the order proj,edge,proj,edge,head —
// idempotent (proj re-zeroes y_acc before the second edge), so outputs are
// identical to a single run. Purpose: dur_us(R3) - dur_us(R2) = proj+edge
// time, resolving whether the 354 µs window is harness-fill overhead
// (theory A) or contains ~150 µs of chain slack (theory B).
// ===========================================================================

#define HID    64
#define HEADS  8
#define MOL_N  40
#define PRO_N  400
#define NGRAPH 256

typedef float vfloat4 __attribute__((ext_vector_type(4)));

__device__ __forceinline__ float elu_plus(float x, float c) {
    // elu(x) + c, alpha=1
    return x > 0.0f ? x + c : __expf(x) - 1.0f + c;
}

// ---------------------------------------------------------------------------
// Kernel 1: per-node projections.
// ---------------------------------------------------------------------------
__global__ __launch_bounds__(256) void proj_kernel(
    const float* __restrict__ mol_feats, const float* __restrict__ pro_feats,
    const float* __restrict__ spatial,   const float* __restrict__ sigma_w,
    const float* __restrict__ sigma_b,   const float* __restrict__ mu_w,
    const float* __restrict__ mu_b,
    float* __restrict__ mol_s, float* __restrict__ mol_m,
    float* __restrict__ pro_s, float* __restrict__ pro_m,
    float* __restrict__ y_acc, int mol_blocks)
{
    __shared__ float rows[32][HID + 1];     // +1 pad: breaks 32-bank aliasing
    __shared__ float wsig[HID][HEADS];
    __shared__ float wmu [HID][HEADS];

    const int tid = threadIdx.x;
    const bool is_mol = (int)blockIdx.x < mol_blocks;

    if (blockIdx.x == 0) {
        for (int i = tid; i < NGRAPH * HEADS; i += 256) y_acc[i] = 0.0f;
    }

    // stage weights (mol: rows [0,64); pro: rows [64,128))
    const int wofs = is_mol ? 0 : HID * HEADS;
    for (int i = tid; i < HID * HEADS; i += 256) {
        wsig[i / HEADS][i % HEADS] = sigma_w[wofs + i];
        wmu [i / HEADS][i % HEADS] = mu_w  [wofs + i];
    }

    // stage 32 input rows (float4-vectorized, coalesced)
    const int r0 = (is_mol ? (int)blockIdx.x : ((int)blockIdx.x - mol_blocks)) * 32;
    if (is_mol) {
        const float4* src = (const float4*)mol_feats + (size_t)r0 * (HID / 4);
        for (int i = tid; i < 32 * (HID / 4); i += 256) {
            float4 v = src[i];
            int lr = i / (HID / 4), k4 = (i % (HID / 4)) * 4;
            rows[lr][k4 + 0] = v.x; rows[lr][k4 + 1] = v.y;
            rows[lr][k4 + 2] = v.z; rows[lr][k4 + 3] = v.w;
        }
    } else {
        const float4* srcp = (const float4*)pro_feats + (size_t)r0 * (HID / 4);
        const float4* srcs = (const float4*)spatial   + (size_t)r0 * (HID / 4);
        for (int i = tid; i < 32 * (HID / 4); i += 256) {
            float4 a = srcp[i];
            float4 b = srcs[i];
            int lr = i / (HID / 4), k4 = (i % (HID / 4)) * 4;
            rows[lr][k4 + 0] = a.x * b.x; rows[lr][k4 + 1] = a.y * b.y;
            rows[lr][k4 + 2] = a.z * b.z; rows[lr][k4 + 3] = a.w * b.w;
        }
    }
    __syncthreads();

    const int lr = tid >> 3;      // local row
    const int h  = tid & 7;       // head
    float as = 0.0f, am = 0.0f;
#pragma unroll
    for (int k = 0; k < HID; ++k) {
        float x = rows[lr][k];
        as += x * wsig[k][h];
        am += x * wmu [k][h];
    }
    const int gr = r0 + lr;
    if (is_mol) {
        mol_s[gr * HEADS + h] = as + sigma_b[h];   // fold biases into mol side
        mol_m[gr * HEADS + h] = am + mu_b[h];
    } else {
        pro_s[gr * HEADS + h] = as;
        pro_m[gr * HEADS + h] = am;
    }
}

// ---------------------------------------------------------------------------
// Kernel 2: edge map + mu segment-sum. Grid swizzled: b = blockIdx & 255
// keeps all 40 blocks of a complex on one XCD for L2 table locality.
// ---------------------------------------------------------------------------
__global__ __launch_bounds__(256) void edge_kernel(
    const float* __restrict__ mol_s, const float* __restrict__ mol_m,
    const float* __restrict__ pro_s, const float* __restrict__ pro_m,
    float* __restrict__ mu_out, float* __restrict__ sg_out,
    float* __restrict__ y_acc)
{
    const int bi  = blockIdx.x;
    const int b   = bi & (NGRAPH - 1);   // complex id
    const int r   = bi >> 8;             // atom within complex
    const int m   = b * MOL_N + r;       // global mol row
    const int tid = threadIdx.x;

    __shared__ float s_mol[16];    // [0:8) = mol_s row, [8:16) = mol_m row
    __shared__ float s_hsum[HEADS];
    if (tid < 8)       s_mol[tid] = mol_s[m * HEADS + tid];
    else if (tid < 16) s_mol[tid] = mol_m[m * HEADS + (tid - 8)];
    if (tid < HEADS)   s_hsum[tid] = 0.0f;
    __syncthreads();

    const int q = tid & 1;         // head half: heads q*4 .. q*4+3
    float ms[4], mm[4];
#pragma unroll
    for (int k = 0; k < 4; ++k) {
        ms[k] = s_mol[q * 4 + k];
        mm[k] = s_mol[8 + q * 4 + k];
    }

    const vfloat4* pm4 = (const vfloat4*)pro_m + (size_t)b * PRO_N * 2;
    const vfloat4* ps4 = (const vfloat4*)pro_s + (size_t)b * PRO_N * 2;
    vfloat4* mu4 = (vfloat4*)mu_out + (size_t)m * PRO_N * 2;
    vfloat4* sg4 = (vfloat4*)sg_out + (size_t)m * PRO_N * 2;

    float acc[4] = {0.f, 0.f, 0.f, 0.f};
    for (int t = tid; t < PRO_N * 2; t += 256) {   // t = j*2 + q, q constant/thread
        vfloat4 pmv = pm4[t];
        vfloat4 psv = ps4[t];
        vfloat4 vmu, vsg;
        vmu.x = elu_plus(pmv.x + mm[0], 1.0f);
        vmu.y = elu_plus(pmv.y + mm[1], 1.0f);
        vmu.z = elu_plus(pmv.z + mm[2], 1.0f);
        vmu.w = elu_plus(pmv.w + mm[3], 1.0f);
        vsg.x = elu_plus(psv.x + ms[0], 1.1f);
        vsg.y = elu_plus(psv.y + ms[1], 1.1f);
        vsg.z = elu_plus(psv.z + ms[2], 1.1f);
        vsg.w = elu_plus(psv.w + ms[3], 1.1f);
        mu4[t] = vmu;
        sg4[t] = vsg;
        acc[0] += vmu.x; acc[1] += vmu.y; acc[2] += vmu.z; acc[3] += vmu.w;
    }

    // reduce mu partials: butterfly over lanes of same parity (masks 2..32)
#pragma unroll
    for (int mask = 2; mask < 64; mask <<= 1) {
#pragma unroll
        for (int k = 0; k < 4; ++k) acc[k] += __shfl_xor(acc[k], mask, 64);
    }
    if ((tid & 63) < 2) {          // lane 0 (heads 0-3) and lane 1 (heads 4-7)
#pragma unroll
        for (int k = 0; k < 4; ++k) atomicAdd(&s_hsum[q * 4 + k], acc[k]);
    }
    __syncthreads();
    if (tid < HEADS) atomicAdd(&y_acc[b * HEADS + tid], s_hsum[tid]);
}

// ---------------------------------------------------------------------------
// Kernel 3: per-graph MLP head. One thread per graph.
// ---------------------------------------------------------------------------
__global__ __launch_bounds__(256) void head_kernel(
    const float* __restrict__ y_acc, const float* __restrict__ w1,
    const float* __restrict__ b1,    const float* __restrict__ w2,
    const float* __restrict__ b2,    float* __restrict__ y_pred)
{
    const int g = threadIdx.x;
    float y[HEADS];
#pragma unroll
    for (int h = 0; h < HEADS; ++h) y[h] = y_acc[g * HEADS + h] * 0.001f;
    float out = b2[0];
#pragma unroll
    for (int o = 0; o < 2 * HEADS; ++o) {
        float a = b1[o];
#pragma unroll
        for (int h = 0; h < HEADS; ++h) a += y[h] * w1[h * (2 * HEADS) + o];
        a = a > 0.0f ? a : __expf(a) - 1.0f;   // elu
        out += a * w2[o];
    }
    y_pred[g] = out;
}

extern "C" void kernel_launch(void* const* d_in, const int* in_sizes, int n_in,
                              void* d_out, int out_size, void* d_ws, size_t ws_size,
                              hipStream_t stream) {
    const float* mol_feats = (const float*)d_in[0];
    const float* pro_feats = (const float*)d_in[1];
    const float* spatial   = (const float*)d_in[2];
    const float* sigma_w   = (const float*)d_in[3];
    const float* sigma_b   = (const float*)d_in[4];
    const float* mu_w      = (const float*)d_in[5];
    const float* mu_b      = (const float*)d_in[6];
    const float* w1        = (const float*)d_in[7];
    const float* b1        = (const float*)d_in[8];
    const float* w2        = (const float*)d_in[9];
    const float* b2        = (const float*)d_in[10];

    const int M = in_sizes[0] / HID;    // 10240
    const int P = in_sizes[1] / HID;    // 102400
    const int E = in_sizes[11];         // 4,096,000 (mol_index length)

    // workspace layout (all float, 16B-aligned slices)
    float* ws    = (float*)d_ws;
    float* mol_s = ws;                         // M*8
    float* mol_m = mol_s + (size_t)M * HEADS;  // M*8
    float* pro_s = mol_m + (size_t)M * HEADS;  // P*8
    float* pro_m = pro_s + (size_t)P * HEADS;  // P*8
    float* y_acc = pro_m + (size_t)P * HEADS;  // NGRAPH*8

    float* mu_out = (float*)d_out;
    float* sg_out = mu_out + (size_t)E * HEADS;
    float* y_pred = sg_out + (size_t)E * HEADS;

    const int mol_blocks = M / 32;
    const int pro_blocks = P / 32;

    // ---- pass 1 ----
    proj_kernel<<<mol_blocks + pro_blocks, 256, 0, stream>>>(
        mol_feats, pro_feats, spatial, sigma_w, sigma_b, mu_w, mu_b,
        mol_s, mol_m, pro_s, pro_m, y_acc, mol_blocks);
    edge_kernel<<<M, 256, 0, stream>>>(
        mol_s, mol_m, pro_s, pro_m, mu_out, sg_out, y_acc);

    // ---- pass 2 (identical; proj re-zeroes y_acc, edge re-accumulates) ----
    proj_kernel<<<mol_blocks + pro_blocks, 256, 0, stream>>>(
        mol_feats, pro_feats, spatial, sigma_w, sigma_b, mu_w, mu_b,
        mol_s, mol_m, pro_s, pro_m, y_acc, mol_blocks);
    edge_kernel<<<M, 256, 0, stream>>>(
        mol_s, mol_m, pro_s, pro_m, mu_out, sg_out, y_acc);

    head_kernel<<<1, 256, 0, stream>>>(y_acc, w1, b1, w2, b2, y_pred);
}

// Round 4
// 357.686 us; speedup vs baseline: 1.1975x; 1.1975x over previous
//
#include <hip/hip_runtime.h>

// ===========================================================================
// R4: single-pass chain (revert of the R3 doubling diagnostic) + proj
// register-blocking. Measured context (R3 calibration): proj+edge = 71.4 µs,
// harness fixed overhead ~282 µs of the 354 µs window. Edge is write-bound
// (~45 µs, 262 MB mandatory output). This round targets proj's LDS-read-
// heavy inner loop (was 3x ds_read_b32 + 2 FMA per k).
// ===========================================================================

#define HID    64
#define HEADS  8
#define MOL_N  40
#define PRO_N  400
#define NGRAPH 256

typedef float vfloat4 __attribute__((ext_vector_type(4)));

__device__ __forceinline__ float elu_plus(float x, float c) {
    // elu(x) + c, alpha=1
    return x > 0.0f ? x + c : __expf(x) - 1.0f + c;
}

// ---------------------------------------------------------------------------
// Kernel 1: per-node projections, 64 rows/block, 2 rows/thread.
//   thread (lr = tid>>3 in [0,32), h = tid&7) computes rows lr and lr+32.
//   Row tile staged in LDS with stride 68 floats (= 272 B = 17*16 B):
//     - 16B-aligned => ds_read_b128 legal
//     - compute-read banks: word = lr*68 + 4*k4; 68 % 32 == 4, so the 8
//       distinct row addresses per wave start at banks {0,4,...,28} * 4-wide
//       => all 32 banks exactly once, conflict-free broadcast.
//   Weight reads wsig[k][h]: 8 consecutive floats x 8-way broadcast, free.
//   Per wave: 128 (row,head) outputs for 32 b128 + 128 b32 LDS reads —
//   ~2x the old pairs/LDS-cycle (was 192 b32 for 64 outputs).
// ---------------------------------------------------------------------------
__global__ __launch_bounds__(256) void proj_kernel(
    const float* __restrict__ mol_feats, const float* __restrict__ pro_feats,
    const float* __restrict__ spatial,   const float* __restrict__ sigma_w,
    const float* __restrict__ sigma_b,   const float* __restrict__ mu_w,
    const float* __restrict__ mu_b,
    float* __restrict__ mol_s, float* __restrict__ mol_m,
    float* __restrict__ pro_s, float* __restrict__ pro_m,
    float* __restrict__ y_acc, int mol_blocks)
{
    __shared__ float rows[64][68];          // stride 68: aligned + conflict-free
    __shared__ float wsig[HID][HEADS];
    __shared__ float wmu [HID][HEADS];

    const int tid = threadIdx.x;
    const bool is_mol = (int)blockIdx.x < mol_blocks;

    if (blockIdx.x == 0) {
        for (int i = tid; i < NGRAPH * HEADS; i += 256) y_acc[i] = 0.0f;
    }

    // stage weights (mol: rows [0,64) of W; pro: rows [64,128))
    const int wofs = is_mol ? 0 : HID * HEADS;
    for (int i = tid; i < HID * HEADS; i += 256) {
        wsig[i / HEADS][i % HEADS] = sigma_w[wofs + i];
        wmu [i / HEADS][i % HEADS] = mu_w  [wofs + i];
    }

    // stage 64 input rows (float4 loads, coalesced; pro side fuses *spatial)
    const int r0 = (is_mol ? (int)blockIdx.x : ((int)blockIdx.x - mol_blocks)) * 64;
    if (is_mol) {
        const float4* src = (const float4*)mol_feats + (size_t)r0 * (HID / 4);
        for (int i = tid; i < 64 * (HID / 4); i += 256) {
            float4 v = src[i];
            float4* dst = (float4*)&rows[i / (HID / 4)][0];
            dst[i % (HID / 4)] = v;
        }
    } else {
        const float4* srcp = (const float4*)pro_feats + (size_t)r0 * (HID / 4);
        const float4* srcs = (const float4*)spatial   + (size_t)r0 * (HID / 4);
        for (int i = tid; i < 64 * (HID / 4); i += 256) {
            float4 a = srcp[i];
            float4 b = srcs[i];
            float4 v; v.x = a.x * b.x; v.y = a.y * b.y; v.z = a.z * b.z; v.w = a.w * b.w;
            float4* dst = (float4*)&rows[i / (HID / 4)][0];
            dst[i % (HID / 4)] = v;
        }
    }
    __syncthreads();

    const int lr = tid >> 3;      // first row of this thread's pair
    const int h  = tid & 7;       // head
    float as0 = 0.f, am0 = 0.f;   // row lr
    float as1 = 0.f, am1 = 0.f;   // row lr+32
    const float4* rowA = (const float4*)&rows[lr][0];
    const float4* rowB = (const float4*)&rows[lr + 32][0];
#pragma unroll
    for (int k4 = 0; k4 < HID / 4; ++k4) {
        const float4 xa = rowA[k4];
        const float4 xb = rowB[k4];
        const float* wg = &wsig[k4 * 4][h];   // wsig[k4*4+j][h] = wg[8*j]
        const float* wm = &wmu [k4 * 4][h];
        const float w0s = wg[0], w1s = wg[8], w2s = wg[16], w3s = wg[24];
        const float w0m = wm[0], w1m = wm[8], w2m = wm[16], w3m = wm[24];
        as0 += xa.x * w0s; as0 += xa.y * w1s; as0 += xa.z * w2s; as0 += xa.w * w3s;
        am0 += xa.x * w0m; am0 += xa.y * w1m; am0 += xa.z * w2m; am0 += xa.w * w3m;
        as1 += xb.x * w0s; as1 += xb.y * w1s; as1 += xb.z * w2s; as1 += xb.w * w3s;
        am1 += xb.x * w0m; am1 += xb.y * w1m; am1 += xb.z * w2m; am1 += xb.w * w3m;
    }
    const int grA = r0 + lr, grB = r0 + lr + 32;
    if (is_mol) {
        const float sb = sigma_b[h], mb = mu_b[h];     // fold biases, mol side
        mol_s[grA * HEADS + h] = as0 + sb;  mol_m[grA * HEADS + h] = am0 + mb;
        mol_s[grB * HEADS + h] = as1 + sb;  mol_m[grB * HEADS + h] = am1 + mb;
    } else {
        pro_s[grA * HEADS + h] = as0;  pro_m[grA * HEADS + h] = am0;
        pro_s[grB * HEADS + h] = as1;  pro_m[grB * HEADS + h] = am1;
    }
}

// ---------------------------------------------------------------------------
// Kernel 2: edge map + mu segment-sum. Grid swizzled: b = blockIdx & 255
// keeps all 40 blocks of a complex on one XCD for L2 table locality
// (per-XCD table working set 1.6 MB < 4 MB L2).
// R4: mol rows read directly from global (2 wave-uniform 16B addrs ->
// broadcast, L1/L2-served) instead of LDS staging; prologue barrier removed.
// ---------------------------------------------------------------------------
__global__ __launch_bounds__(256) void edge_kernel(
    const float* __restrict__ mol_s, const float* __restrict__ mol_m,
    const float* __restrict__ pro_s, const float* __restrict__ pro_m,
    float* __restrict__ mu_out, float* __restrict__ sg_out,
    float* __restrict__ y_acc)
{
    const int bi  = blockIdx.x;
    const int b   = bi & (NGRAPH - 1);   // complex id
    const int r   = bi >> 8;             // atom within complex
    const int m   = b * MOL_N + r;       // global mol row
    const int tid = threadIdx.x;
    const int q   = tid & 1;             // head half: heads q*4 .. q*4+3

    __shared__ float s_hsum[HEADS];
    if (tid < HEADS) s_hsum[tid] = 0.0f;

    // direct broadcast loads of this atom's projection rows (bias folded)
    const float4 msv = *(const float4*)(mol_s + (size_t)m * HEADS + q * 4);
    const float4 mmv = *(const float4*)(mol_m + (size_t)m * HEADS + q * 4);
    float ms[4] = {msv.x, msv.y, msv.z, msv.w};
    float mm[4] = {mmv.x, mmv.y, mmv.z, mmv.w};

    const vfloat4* pm4 = (const vfloat4*)pro_m + (size_t)b * PRO_N * 2;
    const vfloat4* ps4 = (const vfloat4*)pro_s + (size_t)b * PRO_N * 2;
    vfloat4* mu4 = (vfloat4*)mu_out + (size_t)m * PRO_N * 2;
    vfloat4* sg4 = (vfloat4*)sg_out + (size_t)m * PRO_N * 2;

    float acc[4] = {0.f, 0.f, 0.f, 0.f};
    for (int t = tid; t < PRO_N * 2; t += 256) {   // t = j*2 + q, q constant/thread
        vfloat4 pmv = pm4[t];
        vfloat4 psv = ps4[t];
        vfloat4 vmu, vsg;
        vmu.x = elu_plus(pmv.x + mm[0], 1.0f);
        vmu.y = elu_plus(pmv.y + mm[1], 1.0f);
        vmu.z = elu_plus(pmv.z + mm[2], 1.0f);
        vmu.w = elu_plus(pmv.w + mm[3], 1.0f);
        vsg.x = elu_plus(psv.x + ms[0], 1.1f);
        vsg.y = elu_plus(psv.y + ms[1], 1.1f);
        vsg.z = elu_plus(psv.z + ms[2], 1.1f);
        vsg.w = elu_plus(psv.w + ms[3], 1.1f);
        mu4[t] = vmu;
        sg4[t] = vsg;
        acc[0] += vmu.x; acc[1] += vmu.y; acc[2] += vmu.z; acc[3] += vmu.w;
    }

    // reduce mu partials: butterfly over lanes of same parity (masks 2..32)
#pragma unroll
    for (int mask = 2; mask < 64; mask <<= 1) {
#pragma unroll
        for (int k = 0; k < 4; ++k) acc[k] += __shfl_xor(acc[k], mask, 64);
    }
    __syncthreads();               // s_hsum zeroing visible to all waves
    if ((tid & 63) < 2) {          // lane 0 (heads 0-3) and lane 1 (heads 4-7)
#pragma unroll
        for (int k = 0; k < 4; ++k) atomicAdd(&s_hsum[q * 4 + k], acc[k]);
    }
    __syncthreads();
    if (tid < HEADS) atomicAdd(&y_acc[b * HEADS + tid], s_hsum[tid]);
}

// ---------------------------------------------------------------------------
// Kernel 3: per-graph MLP head. One thread per graph.
// ---------------------------------------------------------------------------
__global__ __launch_bounds__(256) void head_kernel(
    const float* __restrict__ y_acc, const float* __restrict__ w1,
    const float* __restrict__ b1,    const float* __restrict__ w2,
    const float* __restrict__ b2,    float* __restrict__ y_pred)
{
    const int g = threadIdx.x;
    float y[HEADS];
#pragma unroll
    for (int h = 0; h < HEADS; ++h) y[h] = y_acc[g * HEADS + h] * 0.001f;
    float out = b2[0];
#pragma unroll
    for (int o = 0; o < 2 * HEADS; ++o) {
        float a = b1[o];
#pragma unroll
        for (int h = 0; h < HEADS; ++h) a += y[h] * w1[h * (2 * HEADS) + o];
        a = a > 0.0f ? a : __expf(a) - 1.0f;   // elu
        out += a * w2[o];
    }
    y_pred[g] = out;
}

extern "C" void kernel_launch(void* const* d_in, const int* in_sizes, int n_in,
                              void* d_out, int out_size, void* d_ws, size_t ws_size,
                              hipStream_t stream) {
    const float* mol_feats = (const float*)d_in[0];
    const float* pro_feats = (const float*)d_in[1];
    const float* spatial   = (const float*)d_in[2];
    const float* sigma_w   = (const float*)d_in[3];
    const float* sigma_b   = (const float*)d_in[4];
    const float* mu_w      = (const float*)d_in[5];
    const float* mu_b      = (const float*)d_in[6];
    const float* w1        = (const float*)d_in[7];
    const float* b1        = (const float*)d_in[8];
    const float* w2        = (const float*)d_in[9];
    const float* b2        = (const float*)d_in[10];

    const int M = in_sizes[0] / HID;    // 10240
    const int P = in_sizes[1] / HID;    // 102400
    const int E = in_sizes[11];         // 4,096,000 (mol_index length)

    // workspace layout (all float, 16B-aligned slices)
    float* ws    = (float*)d_ws;
    float* mol_s = ws;                         // M*8
    float* mol_m = mol_s + (size_t)M * HEADS;  // M*8
    float* pro_s = mol_m + (size_t)M * HEADS;  // P*8
    float* pro_m = pro_s + (size_t)P * HEADS;  // P*8
    float* y_acc = pro_m + (size_t)P * HEADS;  // NGRAPH*8

    float* mu_out = (float*)d_out;
    float* sg_out = mu_out + (size_t)E * HEADS;
    float* y_pred = sg_out + (size_t)E * HEADS;

    const int mol_blocks = M / 64;      // 160 (M = 10240, exact)
    const int pro_blocks = P / 64;      // 1600 (P = 102400, exact)

    proj_kernel<<<mol_blocks + pro_blocks, 256, 0, stream>>>(
        mol_feats, pro_feats, spatial, sigma_w, sigma_b, mu_w, mu_b,
        mol_s, mol_m, pro_s, pro_m, y_acc, mol_blocks);

    edge_kernel<<<M, 256, 0, stream>>>(
        mol_s, mol_m, pro_s, pro_m, mu_out, sg_out, y_acc);

    head_kernel<<<1, 256, 0, stream>>>(y_acc, w1, b1, w2, b2, y_pred);
}